// Round 1
// baseline (216.457 us; speedup 1.0000x reference)
//
#include <hip/hip_runtime.h>
#include <hip/hip_bf16.h>
#include <cstdint>
#include <cstddef>

// ---------- types ----------
typedef __attribute__((ext_vector_type(8))) short bf16x8;
typedef __attribute__((ext_vector_type(4))) float f32x4;

#define POOLK 12544   // 256 ch * 49 positions

__device__ __forceinline__ void gld16(const void* g, void* l) {
    __builtin_amdgcn_global_load_lds(
        (const __attribute__((address_space(1))) void*)g,
        (__attribute__((address_space(3))) void*)l, 16, 0, 0);
}

__device__ __forceinline__ unsigned short f32_to_bf16(float f) {
    union { float f; unsigned u; } x; x.f = f;
    unsigned r = (x.u + 0x7FFFu + ((x.u >> 16) & 1u)) >> 16;
    return (unsigned short)r;
}

// ---------- ROI align: one block per roi, writes pooled[n][c][i][j] as bf16 ----------
__global__ __launch_bounds__(256) void roi_align_kernel(
    const float* __restrict__ feat2, const float* __restrict__ feat3,
    const float* __restrict__ feat4, const float* __restrict__ feat5,
    const float* __restrict__ rois, unsigned short* __restrict__ pooled)
{
    const int n = blockIdx.x;
    const int tid = threadIdx.x;
    __shared__ int sy0[7], sy1[7], sx0[7], sx1[7];
    __shared__ float swy[7], swx[7], svy[7], svx[7];

    const float rx1 = rois[n*4+0], ry1 = rois[n*4+1];
    const float rx2 = rois[n*4+2], ry2 = rois[n*4+3];
    int lvl = (int)rintf(log2f(sqrtf((ry2-ry1)*(rx2-rx1)) / 224.0f)) + 4;
    lvl = lvl < 2 ? 2 : (lvl > 5 ? 5 : lvl);
    const int H = 256 >> (lvl - 2);          // W == H at every level
    const float Hm1 = (float)(H - 1);
    const float* feat = lvl == 2 ? feat2 : (lvl == 3 ? feat3 : (lvl == 4 ? feat4 : feat5));

    if (tid < 7) {
        const float t = (float)tid / 6.0f;
        const float by1 = ry1 * (1.0f/1024.0f), by2 = ry2 * (1.0f/1024.0f);
        const float bx1 = rx1 * (1.0f/1024.0f), bx2 = rx2 * (1.0f/1024.0f);
        const float ys = (by1 + (by2 - by1) * t) * Hm1;
        const float xs = (bx1 + (bx2 - bx1) * t) * Hm1;
        const float yf = floorf(ys), xf = floorf(xs);
        swy[tid] = ys - yf;  swx[tid] = xs - xf;
        sy0[tid] = (int)fminf(fmaxf(yf,        0.0f), Hm1);
        sy1[tid] = (int)fminf(fmaxf(yf + 1.0f, 0.0f), Hm1);
        sx0[tid] = (int)fminf(fmaxf(xf,        0.0f), Hm1);
        sx1[tid] = (int)fminf(fmaxf(xf + 1.0f, 0.0f), Hm1);
        svy[tid] = (ys >= 0.0f && ys <= Hm1) ? 1.0f : 0.0f;
        svx[tid] = (xs >= 0.0f && xs <= Hm1) ? 1.0f : 0.0f;
    }
    __syncthreads();

    const int HW = H * H;
    unsigned short* orow = pooled + (size_t)n * POOLK;
    for (int e = tid; e < POOLK; e += 256) {
        const int c = e / 49, ij = e % 49, i = ij / 7, j = ij % 7;
        const float* p = feat + c * HW;
        const int y0 = sy0[i], y1 = sy1[i], x0 = sx0[j], x1 = sx1[j];
        const float wy = swy[i], wx = swx[j];
        const float v00 = p[y0*H + x0], v01 = p[y0*H + x1];
        const float v10 = p[y1*H + x0], v11 = p[y1*H + x1];
        float v = v00*(1.0f-wy)*(1.0f-wx) + v01*(1.0f-wy)*wx
                + v10*wy*(1.0f-wx)        + v11*wy*wx;
        v *= svy[i] * svx[j];
        orow[e] = f32_to_bf16(v);
    }
}

// ---------- f32 -> bf16 weight conversion ----------
__global__ void cvt_bf16_kernel(const float* __restrict__ src,
                                unsigned short* __restrict__ dst, int n)
{
    const int i = (blockIdx.x * 256 + threadIdx.x) * 4;
    if (i >= n) return;
    const float4 v = *(const float4*)(src + i);
    ushort4 o;
    o.x = f32_to_bf16(v.x); o.y = f32_to_bf16(v.y);
    o.z = f32_to_bf16(v.z); o.w = f32_to_bf16(v.w);
    *(ushort4*)(dst + i) = o;
}

// ---------- bf16 BT-GEMM, 128x128 tile, BK=32, K-split via blockIdx.z ----------
// C[m][n] = sum_k A[m][k] * B[n][k];  A: M x K row-major, B: N x K row-major.
// Writes f32 partials: Cpart[z][m][n], M = N = 1024 fixed.
__global__ __launch_bounds__(256) void gemm_bt(
    const unsigned short* __restrict__ A, const unsigned short* __restrict__ B,
    float* __restrict__ Cpart, int K, int Kper)
{
    __shared__ __align__(16) unsigned short At[128*32];
    __shared__ __align__(16) unsigned short Bt[128*32];
    const int tid  = threadIdx.x;
    const int lane = tid & 63;
    const int wm = (tid >> 6) >> 1, wn = (tid >> 6) & 1;   // 2x2 waves of 64x64
    const size_t k0 = (size_t)blockIdx.z * Kper;

    // staging: chunk ch (0..511) -> row ch/4, col (ch%4)*8 ; thread covers ch=tid and ch=tid+256
    const int r1 = tid >> 2;
    const int c1 = (tid & 3) * 8;
    const unsigned short* Ag = A + ((size_t)(blockIdx.y * 128 + r1)) * K + k0 + c1;
    const unsigned short* Bg = B + ((size_t)(blockIdx.x * 128 + r1)) * K + k0 + c1;

    f32x4 acc[4][4] = {};
    const int fr = lane & 15;       // fragment row (M/N index within 16)
    const int fq = lane >> 4;       // quad 0..3 -> K-chunk fq*8, D-rows fq*4..+3
    const int colk = fq * 8;

    for (int k = 0; k < Kper; k += 32) {
        gld16(Ag + k,                 &At[(size_t)tid * 8]);
        gld16(Ag + (size_t)64*K + k,  &At[(size_t)(tid + 256) * 8]);
        gld16(Bg + k,                 &Bt[(size_t)tid * 8]);
        gld16(Bg + (size_t)64*K + k,  &Bt[(size_t)(tid + 256) * 8]);
        asm volatile("s_waitcnt vmcnt(0)" ::: "memory");
        __syncthreads();

        bf16x8 a[4], b[4];
#pragma unroll
        for (int mi = 0; mi < 4; ++mi)
            a[mi] = *(const bf16x8*)&At[(wm*64 + mi*16 + fr)*32 + colk];
#pragma unroll
        for (int ni = 0; ni < 4; ++ni)
            b[ni] = *(const bf16x8*)&Bt[(wn*64 + ni*16 + fr)*32 + colk];
#pragma unroll
        for (int mi = 0; mi < 4; ++mi)
#pragma unroll
            for (int ni = 0; ni < 4; ++ni)
                acc[mi][ni] = __builtin_amdgcn_mfma_f32_16x16x32_bf16(
                    a[mi], b[ni], acc[mi][ni], 0, 0, 0);
        __syncthreads();
    }

    float* Cp = Cpart + (size_t)blockIdx.z * (1024*1024);
    const int row0 = blockIdx.y*128 + wm*64;
    const int col0 = blockIdx.x*128 + wn*64;
#pragma unroll
    for (int mi = 0; mi < 4; ++mi)
#pragma unroll
        for (int ni = 0; ni < 4; ++ni)
#pragma unroll
            for (int r = 0; r < 4; ++r)
                Cp[(size_t)(row0 + mi*16 + fq*4 + r) * 1024 + col0 + ni*16 + fr]
                    = acc[mi][ni][r];
}

// ---------- reduce K-split partials + epilogues ----------
__global__ void reduce_bn_kernel(const float* __restrict__ part,
    const float* __restrict__ bias, const float* __restrict__ gamma,
    const float* __restrict__ beta, const float* __restrict__ mean,
    const float* __restrict__ var, unsigned short* __restrict__ out)
{
    const int i = blockIdx.x * 256 + threadIdx.x;
    const int n = i & 1023;
    float v = part[i] + part[i + 1048576] + part[i + 2*1048576] + part[i + 3*1048576];
    v += bias[n];
    v = (v - mean[n]) / sqrtf(var[n] + 0.001f) * gamma[n] + beta[n];
    out[i] = f32_to_bf16(v);
}

__global__ void reduce_bias_relu_kernel(const float* __restrict__ part,
    const float* __restrict__ bias, unsigned short* __restrict__ out)
{
    const int i = blockIdx.x * 256 + threadIdx.x;
    const int n = i & 1023;
    float v = part[i] + part[i + 1048576] + part[i + 2*1048576] + part[i + 3*1048576];
    v = fmaxf(v + bias[n], 0.0f);
    out[i] = f32_to_bf16(v);
}

// ---------- cls/bbox heads + softmax: one wave per roi ----------
__global__ __launch_bounds__(256) void head_kernel(
    const unsigned short* __restrict__ h2,
    const float* __restrict__ cls_w, const float* __restrict__ cls_b,
    const float* __restrict__ bbox_w, const float* __restrict__ bbox_b,
    float* __restrict__ out)
{
    const int roi = blockIdx.x * 4 + (threadIdx.x >> 6);
    const int lane = threadIdx.x & 63;
    const unsigned short* hrow = h2 + (size_t)roi * 1024;
    float hv[16];
#pragma unroll
    for (int j = 0; j < 16; ++j)
        hv[j] = __uint_as_float(((unsigned)hrow[lane*16 + j]) << 16);
    float r[10];
#pragma unroll
    for (int o = 0; o < 10; ++o) {
        const float* w = (o < 2) ? (cls_w + o*1024) : (bbox_w + (size_t)(o-2)*1024);
        float s = 0.f;
#pragma unroll
        for (int j = 0; j < 16; ++j) s += hv[j] * w[lane*16 + j];
#pragma unroll
        for (int off = 32; off > 0; off >>= 1) s += __shfl_xor(s, off);
        r[o] = s;
    }
    if (lane == 0) {
        const float l0 = r[0] + cls_b[0], l1 = r[1] + cls_b[1];
        out[roi*2+0] = l0; out[roi*2+1] = l1;
        const float m = fmaxf(l0, l1);
        const float e0 = expf(l0 - m), e1 = expf(l1 - m);
        const float inv = 1.0f / (e0 + e1);
        out[2000 + roi*2 + 0] = e0 * inv;
        out[2000 + roi*2 + 1] = e1 * inv;
#pragma unroll
        for (int q = 0; q < 8; ++q) out[4000 + roi*8 + q] = r[2+q] + bbox_b[q];
    }
}

// ---------- launcher ----------
extern "C" void kernel_launch(void* const* d_in, const int* in_sizes, int n_in,
                              void* d_out, int out_size, void* d_ws, size_t ws_size,
                              hipStream_t stream)
{
    const float* feat2   = (const float*)d_in[0];
    const float* feat3   = (const float*)d_in[1];
    const float* feat4   = (const float*)d_in[2];
    const float* feat5   = (const float*)d_in[3];
    const float* rois    = (const float*)d_in[4];
    const float* conv_w  = (const float*)d_in[5];
    const float* conv_b  = (const float*)d_in[6];
    const float* bn_gamma= (const float*)d_in[7];
    const float* bn_beta = (const float*)d_in[8];
    const float* bn_mean = (const float*)d_in[9];
    const float* bn_var  = (const float*)d_in[10];
    const float* fc1_w   = (const float*)d_in[11];
    const float* fc1_b   = (const float*)d_in[12];
    const float* fc2_w   = (const float*)d_in[13];
    const float* fc2_b   = (const float*)d_in[14];
    const float* cls_w   = (const float*)d_in[15];
    const float* cls_b   = (const float*)d_in[16];
    const float* bbox_w  = (const float*)d_in[17];
    const float* bbox_b  = (const float*)d_in[18];
    float* out = (float*)d_out;

    char* ws = (char*)d_ws;
    size_t off = 0;
    auto alloc = [&](size_t bytes) {
        void* p = ws + off; off += (bytes + 255) & ~(size_t)255; return p;
    };
    unsigned short* pooled   = (unsigned short*)alloc((size_t)1024*POOLK*2);   // 25.7 MB (M padded to 1024)
    unsigned short* convw_bf = (unsigned short*)alloc((size_t)12845056*2);     // 25.7 MB
    unsigned short* fc1w_bf  = (unsigned short*)alloc((size_t)1048576*2);      // 2 MB
    unsigned short* fc2w_bf  = (unsigned short*)alloc((size_t)1048576*2);      // 2 MB
    float*          part     = (float*)alloc((size_t)4*1048576*4);             // 16.8 MB
    unsigned short* ybf      = (unsigned short*)alloc((size_t)1048576*2);      // 2 MB
    unsigned short* h1bf     = (unsigned short*)alloc((size_t)1048576*2);      // 2 MB
    unsigned short* h2bf     = (unsigned short*)alloc((size_t)1048576*2);      // 2 MB

    // weight conversions (graph-safe, no static state)
    hipLaunchKernelGGL(cvt_bf16_kernel, dim3(12845056/4/256), dim3(256), 0, stream,
                       conv_w, convw_bf, 12845056);
    hipLaunchKernelGGL(cvt_bf16_kernel, dim3(1024), dim3(256), 0, stream,
                       fc1_w, fc1w_bf, 1048576);
    hipLaunchKernelGGL(cvt_bf16_kernel, dim3(1024), dim3(256), 0, stream,
                       fc2_w, fc2w_bf, 1048576);

    // zero the 24 pad rows of pooled (rows 1000..1023)
    hipMemsetAsync(pooled + (size_t)1000*POOLK, 0, (size_t)24*POOLK*2, stream);

    // ROI align
    hipLaunchKernelGGL(roi_align_kernel, dim3(1000), dim3(256), 0, stream,
                       feat2, feat3, feat4, feat5, rois, pooled);

    // conv einsum as GEMM: [1024 x 12544] * [1024 x 12544]^T, K-split 4
    hipLaunchKernelGGL(gemm_bt, dim3(8,8,4), dim3(256), 0, stream,
                       pooled, convw_bf, part, 12544, 3136);
    hipLaunchKernelGGL(reduce_bn_kernel, dim3(4096), dim3(256), 0, stream,
                       part, conv_b, bn_gamma, bn_beta, bn_mean, bn_var, ybf);

    // fc1 + relu
    hipLaunchKernelGGL(gemm_bt, dim3(8,8,4), dim3(256), 0, stream,
                       ybf, fc1w_bf, part, 1024, 256);
    hipLaunchKernelGGL(reduce_bias_relu_kernel, dim3(4096), dim3(256), 0, stream,
                       part, fc1_b, h1bf);

    // fc2 + relu
    hipLaunchKernelGGL(gemm_bt, dim3(8,8,4), dim3(256), 0, stream,
                       h1bf, fc2w_bf, part, 1024, 256);
    hipLaunchKernelGGL(reduce_bias_relu_kernel, dim3(4096), dim3(256), 0, stream,
                       part, fc2_b, h2bf);

    // heads + softmax
    hipLaunchKernelGGL(head_kernel, dim3(250), dim3(256), 0, stream,
                       h2bf, cls_w, cls_b, bbox_w, bbox_b, out);
}

// Round 2
// 163.017 us; speedup vs baseline: 1.3278x; 1.3278x over previous
//
#include <hip/hip_runtime.h>
#include <cstdint>
#include <cstddef>

typedef __attribute__((ext_vector_type(8))) short bf16x8;
typedef __attribute__((ext_vector_type(4))) float f32x4;

#define POOLK 12544   // K order: ij*256 + c  (49 positions x 256 channels)

// T (channel-last bf16 feats) level offsets in shorts
#define TOFF2 0
#define TOFF3 16777216
#define TOFF4 20971520
#define TOFF5 22020096
#define TTOT_SH 22282240   // 44,564,480 bytes

__device__ __forceinline__ void gld16(const void* g, void* l) {
    __builtin_amdgcn_global_load_lds(
        (const __attribute__((address_space(1))) void*)g,
        (__attribute__((address_space(3))) void*)l, 16, 0, 0);
}

__device__ __forceinline__ unsigned short f32_to_bf16(float f) {
    union { float f; unsigned u; } x; x.f = f;
    unsigned r = (x.u + 0x7FFFu + ((x.u >> 16) & 1u)) >> 16;
    return (unsigned short)r;
}
__device__ __forceinline__ float bf16_to_f32(unsigned short s) {
    return __uint_as_float(((unsigned)s) << 16);
}

// ---------- feature transpose: [256][H][W] f32 -> [H*W][256] bf16 ----------
__global__ __launch_bounds__(256) void feat_tr_kernel(
    const float* __restrict__ f2, const float* __restrict__ f3,
    const float* __restrict__ f4, const float* __restrict__ f5,
    unsigned short* __restrict__ T)
{
    int b = blockIdx.x;
    const float* src; unsigned short* dst; int P;
    if (b < 2048)      { src = f2; dst = T + TOFF2; P = 65536; }
    else if (b < 2560) { src = f3; dst = T + TOFF3; P = 16384; b -= 2048; }
    else if (b < 2688) { src = f4; dst = T + TOFF4; P = 4096;  b -= 2560; }
    else               { src = f5; dst = T + TOFF5; P = 1024;  b -= 2688; }
    const int p0 = b * 32;
    __shared__ float lds[32][260];
    const int t = threadIdx.x;
    // read: 8 passes x 32 channels; 8 lanes cover one 32-pos row via float4
    const int cr = t >> 3, x4 = (t & 7) * 4;
#pragma unroll
    for (int cc = 0; cc < 8; ++cc) {
        const int c = cc * 32 + cr;
        const float4 v = *(const float4*)(src + (size_t)c * P + p0 + x4);
        lds[x4+0][c] = v.x; lds[x4+1][c] = v.y;
        lds[x4+2][c] = v.z; lds[x4+3][c] = v.w;
    }
    __syncthreads();
    const int c0 = (t & 31) * 8;
#pragma unroll
    for (int pz = 0; pz < 4; ++pz) {
        const int pp = pz * 8 + (t >> 5);
        const float4 a = *(const float4*)&lds[pp][c0];
        const float4 bq = *(const float4*)&lds[pp][c0 + 4];
        bf16x8 o;
        o[0] = (short)f32_to_bf16(a.x);  o[1] = (short)f32_to_bf16(a.y);
        o[2] = (short)f32_to_bf16(a.z);  o[3] = (short)f32_to_bf16(a.w);
        o[4] = (short)f32_to_bf16(bq.x); o[5] = (short)f32_to_bf16(bq.y);
        o[6] = (short)f32_to_bf16(bq.z); o[7] = (short)f32_to_bf16(bq.w);
        *(bf16x8*)(dst + ((size_t)(p0 + pp)) * 256 + c0) = o;
    }
}

// ---------- ROI gather from channel-last T, coalesced; pooled[n][ij*256+c] ----------
__global__ __launch_bounds__(256) void roi_gather_kernel(
    const unsigned short* __restrict__ T, const float* __restrict__ rois,
    unsigned short* __restrict__ pooled)
{
    const int n = blockIdx.x;
    const int tid = threadIdx.x;
    __shared__ int sy0[7], sy1[7], sx0[7], sx1[7];
    __shared__ float swy[7], swx[7], svy[7], svx[7];

    const float rx1 = rois[n*4+0], ry1 = rois[n*4+1];
    const float rx2 = rois[n*4+2], ry2 = rois[n*4+3];
    int lvl = (int)rintf(log2f(sqrtf((ry2-ry1)*(rx2-rx1)) * (1.0f/224.0f))) + 4;
    lvl = lvl < 2 ? 2 : (lvl > 5 ? 5 : lvl);
    const int W = 256 >> (lvl - 2);
    const float Hm1 = (float)(W - 1);
    const unsigned short* Tl = T + (lvl == 2 ? TOFF2 : (lvl == 3 ? TOFF3 : (lvl == 4 ? TOFF4 : TOFF5)));

    if (tid < 7) {
        const float t = (float)tid / 6.0f;
        const float by1 = ry1*(1.0f/1024.0f), by2 = ry2*(1.0f/1024.0f);
        const float bx1 = rx1*(1.0f/1024.0f), bx2 = rx2*(1.0f/1024.0f);
        const float ys = (by1 + (by2 - by1) * t) * Hm1;
        const float xs = (bx1 + (bx2 - bx1) * t) * Hm1;
        const float yf = floorf(ys), xf = floorf(xs);
        swy[tid] = ys - yf;  swx[tid] = xs - xf;
        sy0[tid] = (int)fminf(fmaxf(yf,        0.0f), Hm1);
        sy1[tid] = (int)fminf(fmaxf(yf + 1.0f, 0.0f), Hm1);
        sx0[tid] = (int)fminf(fmaxf(xf,        0.0f), Hm1);
        sx1[tid] = (int)fminf(fmaxf(xf + 1.0f, 0.0f), Hm1);
        svy[tid] = (ys >= 0.0f && ys <= Hm1) ? 1.0f : 0.0f;
        svx[tid] = (xs >= 0.0f && xs <= Hm1) ? 1.0f : 0.0f;
    }
    __syncthreads();

    const int g  = tid >> 5;            // position group (8 in flight)
    const int c0 = (tid & 31) * 8;      // this lane's 8 channels
    unsigned short* orow = pooled + (size_t)n * POOLK;
#pragma unroll
    for (int it = 0; it < 7; ++it) {
        const int pos = it * 8 + g;
        if (pos >= 49) break;
        const int i = pos / 7, j = pos % 7;
        const int y0 = sy0[i], y1 = sy1[i], x0 = sx0[j], x1 = sx1[j];
        const float wy = swy[i], wx = swx[j];
        const float scale = svy[i] * svx[j];
        const bf16x8 v00 = *(const bf16x8*)(Tl + ((size_t)(y0*W + x0))*256 + c0);
        const bf16x8 v01 = *(const bf16x8*)(Tl + ((size_t)(y0*W + x1))*256 + c0);
        const bf16x8 v10 = *(const bf16x8*)(Tl + ((size_t)(y1*W + x0))*256 + c0);
        const bf16x8 v11 = *(const bf16x8*)(Tl + ((size_t)(y1*W + x1))*256 + c0);
        bf16x8 o;
#pragma unroll
        for (int jj = 0; jj < 8; ++jj) {
            const float f00 = bf16_to_f32((unsigned short)v00[jj]);
            const float f01 = bf16_to_f32((unsigned short)v01[jj]);
            const float f10 = bf16_to_f32((unsigned short)v10[jj]);
            const float f11 = bf16_to_f32((unsigned short)v11[jj]);
            const float top = f00 + (f01 - f00) * wx;
            const float bot = f10 + (f11 - f10) * wx;
            o[jj] = (short)f32_to_bf16((top + (bot - top) * wy) * scale);
        }
        *(bf16x8*)(orow + pos * 256 + c0) = o;
    }
}

// ---------- fallback ROI (direct f32 gather), writes pooled[n][ij*256+c] ----------
__global__ __launch_bounds__(256) void roi_direct_kernel(
    const float* __restrict__ feat2, const float* __restrict__ feat3,
    const float* __restrict__ feat4, const float* __restrict__ feat5,
    const float* __restrict__ rois, unsigned short* __restrict__ pooled)
{
    const int n = blockIdx.x;
    const int tid = threadIdx.x;
    __shared__ int sy0[7], sy1[7], sx0[7], sx1[7];
    __shared__ float swy[7], swx[7], svy[7], svx[7];
    const float rx1 = rois[n*4+0], ry1 = rois[n*4+1];
    const float rx2 = rois[n*4+2], ry2 = rois[n*4+3];
    int lvl = (int)rintf(log2f(sqrtf((ry2-ry1)*(rx2-rx1)) * (1.0f/224.0f))) + 4;
    lvl = lvl < 2 ? 2 : (lvl > 5 ? 5 : lvl);
    const int H = 256 >> (lvl - 2);
    const float Hm1 = (float)(H - 1);
    const float* feat = lvl==2 ? feat2 : (lvl==3 ? feat3 : (lvl==4 ? feat4 : feat5));
    if (tid < 7) {
        const float t = (float)tid / 6.0f;
        const float by1 = ry1*(1.0f/1024.0f), by2 = ry2*(1.0f/1024.0f);
        const float bx1 = rx1*(1.0f/1024.0f), bx2 = rx2*(1.0f/1024.0f);
        const float ys = (by1 + (by2-by1)*t) * Hm1;
        const float xs = (bx1 + (bx2-bx1)*t) * Hm1;
        const float yf = floorf(ys), xf = floorf(xs);
        swy[tid] = ys - yf;  swx[tid] = xs - xf;
        sy0[tid] = (int)fminf(fmaxf(yf,      0.0f), Hm1);
        sy1[tid] = (int)fminf(fmaxf(yf+1.0f, 0.0f), Hm1);
        sx0[tid] = (int)fminf(fmaxf(xf,      0.0f), Hm1);
        sx1[tid] = (int)fminf(fmaxf(xf+1.0f, 0.0f), Hm1);
        svy[tid] = (ys >= 0.0f && ys <= Hm1) ? 1.0f : 0.0f;
        svx[tid] = (xs >= 0.0f && xs <= Hm1) ? 1.0f : 0.0f;
    }
    __syncthreads();
    const int HW = H * H;
    unsigned short* orow = pooled + (size_t)n * POOLK;
    for (int e = tid; e < POOLK; e += 256) {
        const int c = e / 49, ij = e % 49, i = ij / 7, j = ij % 7;
        const float* p = feat + c * HW;
        const int y0 = sy0[i], y1 = sy1[i], x0 = sx0[j], x1 = sx1[j];
        const float wy = swy[i], wx = swx[j];
        const float v00 = p[y0*H + x0], v01 = p[y0*H + x1];
        const float v10 = p[y1*H + x0], v11 = p[y1*H + x1];
        float v = v00*(1.0f-wy)*(1.0f-wx) + v01*(1.0f-wy)*wx
                + v10*wy*(1.0f-wx)        + v11*wy*wx;
        v *= svy[i] * svx[j];
        orow[ij*256 + c] = f32_to_bf16(v);   // scattered write (fallback only)
    }
}

// ---------- f32 -> bf16 weight conversion (layout-preserving) ----------
__global__ void cvt_bf16_kernel(const float* __restrict__ src,
                                unsigned short* __restrict__ dst, int n)
{
    const int i = (blockIdx.x * 256 + threadIdx.x) * 4;
    if (i >= n) return;
    const float4 v = *(const float4*)(src + i);
    ushort4 o;
    o.x = f32_to_bf16(v.x); o.y = f32_to_bf16(v.y);
    o.z = f32_to_bf16(v.z); o.w = f32_to_bf16(v.w);
    *(ushort4*)(dst + i) = o;
}

// ---------- conv_w [o][c][ij] f32 -> bf16 [o][ij*256+c] ----------
__global__ __launch_bounds__(256) void convw_tr_kernel(
    const float* __restrict__ src, unsigned short* __restrict__ dst)
{
    const int o = blockIdx.x;
    const int t = threadIdx.x;
    __shared__ unsigned short wlds[POOLK];
    const float* srow = src + (size_t)o * POOLK;
    for (int it = 0; it < 49; ++it) {
        const int idx = it * 256 + t;
        wlds[idx] = f32_to_bf16(srow[idx]);
    }
    __syncthreads();
    unsigned short* drow = dst + (size_t)o * POOLK;
    for (int it = 0; it < 49; ++it) {
        const int k = it * 256 + t;
        const int c = k & 255, ij = k >> 8;
        drow[k] = wlds[c * 49 + ij];
    }
}

// ---------- bf16 BT-GEMM, 128x128 tile, BK=32, split-K, XOR-swizzled LDS ----------
__global__ __launch_bounds__(256) void gemm_bt(
    const unsigned short* __restrict__ A, const unsigned short* __restrict__ B,
    float* __restrict__ Cpart, int K, int Kper)
{
    __shared__ __align__(16) unsigned short At[128*32];
    __shared__ __align__(16) unsigned short Bt[128*32];
    const int tid  = threadIdx.x;
    const int lane = tid & 63;
    const int wm = (tid >> 6) >> 1, wn = (tid >> 6) & 1;
    const size_t k0 = (size_t)blockIdx.z * Kper;

    const int r1 = tid >> 2;
    const int q  = tid & 3;
    const int csw = (q ^ (r1 & 3)) * 8;     // pre-swizzled source column
    const unsigned short* Ag = A + ((size_t)(blockIdx.y * 128 + r1)) * K + k0 + csw;
    const unsigned short* Bg = B + ((size_t)(blockIdx.x * 128 + r1)) * K + k0 + csw;

    f32x4 acc[4][4] = {};
    const int fr = lane & 15;
    const int fq = lane >> 4;
    const int colk = (fq ^ (fr & 3)) * 8;   // swizzled read slot

    for (int k = 0; k < Kper; k += 32) {
        gld16(Ag + k,                 &At[(size_t)tid * 8]);
        gld16(Ag + (size_t)64*K + k,  &At[(size_t)(tid + 256) * 8]);
        gld16(Bg + k,                 &Bt[(size_t)tid * 8]);
        gld16(Bg + (size_t)64*K + k,  &Bt[(size_t)(tid + 256) * 8]);
        asm volatile("s_waitcnt vmcnt(0)" ::: "memory");
        __syncthreads();

        bf16x8 a[4], b[4];
#pragma unroll
        for (int mi = 0; mi < 4; ++mi)
            a[mi] = *(const bf16x8*)&At[(wm*64 + mi*16 + fr)*32 + colk];
#pragma unroll
        for (int ni = 0; ni < 4; ++ni)
            b[ni] = *(const bf16x8*)&Bt[(wn*64 + ni*16 + fr)*32 + colk];
#pragma unroll
        for (int mi = 0; mi < 4; ++mi)
#pragma unroll
            for (int ni = 0; ni < 4; ++ni)
                acc[mi][ni] = __builtin_amdgcn_mfma_f32_16x16x32_bf16(
                    a[mi], b[ni], acc[mi][ni], 0, 0, 0);
        __syncthreads();
    }

    float* Cp = Cpart + (size_t)blockIdx.z * (1024*1024);
    const int row0 = blockIdx.y*128 + wm*64;
    const int col0 = blockIdx.x*128 + wn*64;
#pragma unroll
    for (int mi = 0; mi < 4; ++mi)
#pragma unroll
        for (int ni = 0; ni < 4; ++ni)
#pragma unroll
            for (int r = 0; r < 4; ++r)
                Cp[(size_t)(row0 + mi*16 + fq*4 + r) * 1024 + col0 + ni*16 + fr]
                    = acc[mi][ni][r];
}

// ---------- reduce split-K partials + BN -> bf16 ----------
__global__ void reduce_bn_kernel(const float* __restrict__ part,
    const float* __restrict__ bias, const float* __restrict__ gamma,
    const float* __restrict__ beta, const float* __restrict__ mean,
    const float* __restrict__ var, unsigned short* __restrict__ out, int nz)
{
    const int i = blockIdx.x * 256 + threadIdx.x;
    const int n = i & 1023;
    float v = 0.0f;
    for (int z = 0; z < nz; ++z) v += part[(size_t)z * 1048576 + i];
    v += bias[n];
    v = (v - mean[n]) / sqrtf(var[n] + 0.001f) * gamma[n] + beta[n];
    out[i] = f32_to_bf16(v);
}

// ---------- fused 64x64 FC GEMM (K=1024): bias + optional ReLU, bf16 out ----------
__global__ __launch_bounds__(256) void gemm64_fused(
    const unsigned short* __restrict__ A, const unsigned short* __restrict__ B,
    const float* __restrict__ bias, unsigned short* __restrict__ out, int relu)
{
    __shared__ __align__(16) unsigned short At[64*32];
    __shared__ __align__(16) unsigned short Bt[64*32];
    const int tid = threadIdx.x, lane = tid & 63;
    const int w = tid >> 6, wm = w >> 1, wn = w & 1;
    const int r1 = tid >> 2, q = tid & 3;
    const int csw = (q ^ (r1 & 3)) * 8;
    const unsigned short* Ag = A + (size_t)(blockIdx.y*64 + r1) * 1024 + csw;
    const unsigned short* Bg = B + (size_t)(blockIdx.x*64 + r1) * 1024 + csw;
    const int fr = lane & 15, fq = lane >> 4;
    const int colk = (fq ^ (fr & 3)) * 8;
    f32x4 acc[2][2] = {};
    for (int k = 0; k < 1024; k += 32) {
        gld16(Ag + k, &At[(size_t)tid * 8]);
        gld16(Bg + k, &Bt[(size_t)tid * 8]);
        asm volatile("s_waitcnt vmcnt(0)" ::: "memory");
        __syncthreads();
        bf16x8 a[2], b[2];
#pragma unroll
        for (int mi = 0; mi < 2; ++mi)
            a[mi] = *(const bf16x8*)&At[(wm*32 + mi*16 + fr)*32 + colk];
#pragma unroll
        for (int ni = 0; ni < 2; ++ni)
            b[ni] = *(const bf16x8*)&Bt[(wn*32 + ni*16 + fr)*32 + colk];
#pragma unroll
        for (int mi = 0; mi < 2; ++mi)
#pragma unroll
            for (int ni = 0; ni < 2; ++ni)
                acc[mi][ni] = __builtin_amdgcn_mfma_f32_16x16x32_bf16(
                    a[mi], b[ni], acc[mi][ni], 0, 0, 0);
        __syncthreads();
    }
    const int row0 = blockIdx.y*64 + wm*32;
    const int col0 = blockIdx.x*64 + wn*32;
#pragma unroll
    for (int mi = 0; mi < 2; ++mi)
#pragma unroll
        for (int ni = 0; ni < 2; ++ni)
#pragma unroll
            for (int r = 0; r < 4; ++r) {
                const int row = row0 + mi*16 + fq*4 + r;
                const int col = col0 + ni*16 + fr;
                float v = acc[mi][ni][r] + bias[col];
                if (relu) v = fmaxf(v, 0.0f);
                out[(size_t)row * 1024 + col] = f32_to_bf16(v);
            }
}

// ---------- cls/bbox heads + softmax: one wave per roi ----------
__global__ __launch_bounds__(256) void head_kernel(
    const unsigned short* __restrict__ h2,
    const float* __restrict__ cls_w, const float* __restrict__ cls_b,
    const float* __restrict__ bbox_w, const float* __restrict__ bbox_b,
    float* __restrict__ out)
{
    const int roi = blockIdx.x * 4 + (threadIdx.x >> 6);
    const int lane = threadIdx.x & 63;
    const unsigned short* hrow = h2 + (size_t)roi * 1024;
    float hv[16];
#pragma unroll
    for (int j = 0; j < 16; ++j)
        hv[j] = bf16_to_f32(hrow[lane*16 + j]);
    float r[10];
#pragma unroll
    for (int o = 0; o < 10; ++o) {
        const float* w = (o < 2) ? (cls_w + o*1024) : (bbox_w + (size_t)(o-2)*1024);
        float s = 0.f;
#pragma unroll
        for (int j = 0; j < 16; ++j) s += hv[j] * w[lane*16 + j];
#pragma unroll
        for (int off = 32; off > 0; off >>= 1) s += __shfl_xor(s, off);
        r[o] = s;
    }
    if (lane == 0) {
        const float l0 = r[0] + cls_b[0], l1 = r[1] + cls_b[1];
        out[roi*2+0] = l0; out[roi*2+1] = l1;
        const float m = fmaxf(l0, l1);
        const float e0 = expf(l0 - m), e1 = expf(l1 - m);
        const float inv = 1.0f / (e0 + e1);
        out[2000 + roi*2 + 0] = e0 * inv;
        out[2000 + roi*2 + 1] = e1 * inv;
#pragma unroll
        for (int q = 0; q < 8; ++q) out[4000 + roi*8 + q] = r[2+q] + bbox_b[q];
    }
}

// ---------- launcher ----------
extern "C" void kernel_launch(void* const* d_in, const int* in_sizes, int n_in,
                              void* d_out, int out_size, void* d_ws, size_t ws_size,
                              hipStream_t stream)
{
    const float* feat2   = (const float*)d_in[0];
    const float* feat3   = (const float*)d_in[1];
    const float* feat4   = (const float*)d_in[2];
    const float* feat5   = (const float*)d_in[3];
    const float* rois    = (const float*)d_in[4];
    const float* conv_w  = (const float*)d_in[5];
    const float* conv_b  = (const float*)d_in[6];
    const float* bn_gamma= (const float*)d_in[7];
    const float* bn_beta = (const float*)d_in[8];
    const float* bn_mean = (const float*)d_in[9];
    const float* bn_var  = (const float*)d_in[10];
    const float* fc1_w   = (const float*)d_in[11];
    const float* fc1_b   = (const float*)d_in[12];
    const float* fc2_w   = (const float*)d_in[13];
    const float* fc2_b   = (const float*)d_in[14];
    const float* cls_w   = (const float*)d_in[15];
    const float* cls_b   = (const float*)d_in[16];
    const float* bbox_w  = (const float*)d_in[17];
    const float* bbox_b  = (const float*)d_in[18];
    float* out = (float*)d_out;

    // ---- tiered split-K / layout selection by workspace size ----
    const size_t otherBytes = (size_t)25690112 + 25690112
                            + 5 * (size_t)2097152;            // pooled, convw, fc1w, fc2w, ybf, h1, h2
    const size_t need14 = otherBytes + (size_t)14 * 4194304;  // 120,586,240
    const size_t need8  = otherBytes + (size_t)44564480;      // 106,430,464 (T region dominates)
    int tier;
    size_t regionA;
    int nzc, Kper;
    if (ws_size >= need14)      { tier = 1; regionA = (size_t)14 * 4194304; nzc = 14; Kper = 896;  }
    else if (ws_size >= need8)  { tier = 2; regionA = (size_t)44564480;     nzc = 8;  Kper = 1568; }
    else                        { tier = 3; regionA = (size_t)4  * 4194304; nzc = 4;  Kper = 3136; }

    char* ws = (char*)d_ws;
    size_t off = 0;
    auto alloc = [&](size_t bytes) {
        void* p = ws + off; off += (bytes + 255) & ~(size_t)255; return p;
    };
    char* rA = (char*)alloc(regionA);            // T feats (early) aliased by part (late)
    unsigned short* T    = (unsigned short*)rA;
    float*          part = (float*)rA;
    unsigned short* pooled   = (unsigned short*)alloc((size_t)1024 * POOLK * 2);
    unsigned short* convw_bf = (unsigned short*)alloc((size_t)1024 * POOLK * 2);
    unsigned short* fc1w_bf  = (unsigned short*)alloc((size_t)1048576 * 2);
    unsigned short* fc2w_bf  = (unsigned short*)alloc((size_t)1048576 * 2);
    unsigned short* ybf      = (unsigned short*)alloc((size_t)1048576 * 2);
    unsigned short* h1bf     = (unsigned short*)alloc((size_t)1048576 * 2);
    unsigned short* h2bf     = (unsigned short*)alloc((size_t)1048576 * 2);

    // weight conversions
    hipLaunchKernelGGL(cvt_bf16_kernel, dim3(1024), dim3(256), 0, stream,
                       fc1_w, fc1w_bf, 1048576);
    hipLaunchKernelGGL(cvt_bf16_kernel, dim3(1024), dim3(256), 0, stream,
                       fc2_w, fc2w_bf, 1048576);
    hipLaunchKernelGGL(convw_tr_kernel, dim3(1024), dim3(256), 0, stream,
                       conv_w, convw_bf);

    // zero pad rows 1000..1023 of pooled
    hipMemsetAsync(pooled + (size_t)1000 * POOLK, 0, (size_t)24 * POOLK * 2, stream);

    if (tier <= 2) {
        hipLaunchKernelGGL(feat_tr_kernel, dim3(2720), dim3(256), 0, stream,
                           feat2, feat3, feat4, feat5, T);
        hipLaunchKernelGGL(roi_gather_kernel, dim3(1000), dim3(256), 0, stream,
                           T, rois, pooled);
    } else {
        hipLaunchKernelGGL(roi_direct_kernel, dim3(1000), dim3(256), 0, stream,
                           feat2, feat3, feat4, feat5, rois, pooled);
    }

    // conv einsum GEMM: [1024 x 12544] * [1024 x 12544]^T, split-K
    hipLaunchKernelGGL(gemm_bt, dim3(8, 8, nzc), dim3(256), 0, stream,
                       pooled, convw_bf, part, POOLK, Kper);
    hipLaunchKernelGGL(reduce_bn_kernel, dim3(4096), dim3(256), 0, stream,
                       part, conv_b, bn_gamma, bn_beta, bn_mean, bn_var, ybf, nzc);

    // fc1 + relu (fused epilogue)
    hipLaunchKernelGGL(gemm64_fused, dim3(16, 16), dim3(256), 0, stream,
                       ybf, fc1w_bf, fc1_b, h1bf, 1);
    // fc2 + relu
    hipLaunchKernelGGL(gemm64_fused, dim3(16, 16), dim3(256), 0, stream,
                       h1bf, fc2w_bf, fc2_b, h2bf, 1);

    // heads + softmax
    hipLaunchKernelGGL(head_kernel, dim3(250), dim3(256), 0, stream,
                       h2bf, cls_w, cls_b, bbox_w, bbox_b, out);
}

// Round 3
// 132.714 us; speedup vs baseline: 1.6310x; 1.2283x over previous
//
#include <hip/hip_runtime.h>
#include <cstdint>
#include <cstddef>

typedef __attribute__((ext_vector_type(8))) short bf16x8;
typedef __attribute__((ext_vector_type(4))) float f32x4;

#define POOLK 12544   // K order: ij*256 + c  (49 positions x 256 channels)

// T (channel-last bf16 feats) level offsets in shorts
#define TOFF2 0
#define TOFF3 16777216
#define TOFF4 20971520
#define TOFF5 22020096
#define TTOT_SH 22282240   // 44,564,480 bytes

__device__ __forceinline__ void gld16(const void* g, void* l) {
    __builtin_amdgcn_global_load_lds(
        (const __attribute__((address_space(1))) void*)g,
        (__attribute__((address_space(3))) void*)l, 16, 0, 0);
}

__device__ __forceinline__ unsigned short f32_to_bf16(float f) {
    union { float f; unsigned u; } x; x.f = f;
    unsigned r = (x.u + 0x7FFFu + ((x.u >> 16) & 1u)) >> 16;
    return (unsigned short)r;
}
__device__ __forceinline__ float bf16_to_f32(unsigned short s) {
    return __uint_as_float(((unsigned)s) << 16);
}

// ---------- feature transpose: [256][H][W] f32 -> [H*W][256] bf16 ----------
__global__ __launch_bounds__(256) void feat_tr_kernel(
    const float* __restrict__ f2, const float* __restrict__ f3,
    const float* __restrict__ f4, const float* __restrict__ f5,
    unsigned short* __restrict__ T)
{
    int b = blockIdx.x;
    const float* src; unsigned short* dst; int P;
    if (b < 2048)      { src = f2; dst = T + TOFF2; P = 65536; }
    else if (b < 2560) { src = f3; dst = T + TOFF3; P = 16384; b -= 2048; }
    else if (b < 2688) { src = f4; dst = T + TOFF4; P = 4096;  b -= 2560; }
    else               { src = f5; dst = T + TOFF5; P = 1024;  b -= 2688; }
    const int p0 = b * 32;
    __shared__ float lds[32][260];
    const int t = threadIdx.x;
    const int cr = t >> 3, x4 = (t & 7) * 4;
#pragma unroll
    for (int cc = 0; cc < 8; ++cc) {
        const int c = cc * 32 + cr;
        const float4 v = *(const float4*)(src + (size_t)c * P + p0 + x4);
        lds[x4+0][c] = v.x; lds[x4+1][c] = v.y;
        lds[x4+2][c] = v.z; lds[x4+3][c] = v.w;
    }
    __syncthreads();
    const int c0 = (t & 31) * 8;
#pragma unroll
    for (int pz = 0; pz < 4; ++pz) {
        const int pp = pz * 8 + (t >> 5);
        const float4 a = *(const float4*)&lds[pp][c0];
        const float4 bq = *(const float4*)&lds[pp][c0 + 4];
        bf16x8 o;
        o[0] = (short)f32_to_bf16(a.x);  o[1] = (short)f32_to_bf16(a.y);
        o[2] = (short)f32_to_bf16(a.z);  o[3] = (short)f32_to_bf16(a.w);
        o[4] = (short)f32_to_bf16(bq.x); o[5] = (short)f32_to_bf16(bq.y);
        o[6] = (short)f32_to_bf16(bq.z); o[7] = (short)f32_to_bf16(bq.w);
        *(bf16x8*)(dst + ((size_t)(p0 + pp)) * 256 + c0) = o;
    }
}

// ---------- ROI gather from channel-last T; pooled[n][ij*256+c] ----------
__global__ __launch_bounds__(256) void roi_gather_kernel(
    const unsigned short* __restrict__ T, const float* __restrict__ rois,
    unsigned short* __restrict__ pooled)
{
    const int n = blockIdx.x;
    const int tid = threadIdx.x;
    __shared__ int sy0[7], sy1[7], sx0[7], sx1[7];
    __shared__ float swy[7], swx[7], svy[7], svx[7];

    const float rx1 = rois[n*4+0], ry1 = rois[n*4+1];
    const float rx2 = rois[n*4+2], ry2 = rois[n*4+3];
    int lvl = (int)rintf(log2f(sqrtf((ry2-ry1)*(rx2-rx1)) * (1.0f/224.0f))) + 4;
    lvl = lvl < 2 ? 2 : (lvl > 5 ? 5 : lvl);
    const int W = 256 >> (lvl - 2);
    const float Hm1 = (float)(W - 1);
    const unsigned short* Tl = T + (lvl == 2 ? TOFF2 : (lvl == 3 ? TOFF3 : (lvl == 4 ? TOFF4 : TOFF5)));

    if (tid < 7) {
        const float t = (float)tid / 6.0f;
        const float by1 = ry1*(1.0f/1024.0f), by2 = ry2*(1.0f/1024.0f);
        const float bx1 = rx1*(1.0f/1024.0f), bx2 = rx2*(1.0f/1024.0f);
        const float ys = (by1 + (by2 - by1) * t) * Hm1;
        const float xs = (bx1 + (bx2 - bx1) * t) * Hm1;
        const float yf = floorf(ys), xf = floorf(xs);
        swy[tid] = ys - yf;  swx[tid] = xs - xf;
        sy0[tid] = (int)fminf(fmaxf(yf,        0.0f), Hm1);
        sy1[tid] = (int)fminf(fmaxf(yf + 1.0f, 0.0f), Hm1);
        sx0[tid] = (int)fminf(fmaxf(xf,        0.0f), Hm1);
        sx1[tid] = (int)fminf(fmaxf(xf + 1.0f, 0.0f), Hm1);
        svy[tid] = (ys >= 0.0f && ys <= Hm1) ? 1.0f : 0.0f;
        svx[tid] = (xs >= 0.0f && xs <= Hm1) ? 1.0f : 0.0f;
    }
    __syncthreads();

    const int g  = tid >> 5;
    const int c0 = (tid & 31) * 8;
    unsigned short* orow = pooled + (size_t)n * POOLK;
#pragma unroll
    for (int it = 0; it < 7; ++it) {
        const int pos = it * 8 + g;
        if (pos >= 49) break;
        const int i = pos / 7, j = pos % 7;
        const int y0 = sy0[i], y1 = sy1[i], x0 = sx0[j], x1 = sx1[j];
        const float wy = swy[i], wx = swx[j];
        const float scale = svy[i] * svx[j];
        const bf16x8 v00 = *(const bf16x8*)(Tl + ((size_t)(y0*W + x0))*256 + c0);
        const bf16x8 v01 = *(const bf16x8*)(Tl + ((size_t)(y0*W + x1))*256 + c0);
        const bf16x8 v10 = *(const bf16x8*)(Tl + ((size_t)(y1*W + x0))*256 + c0);
        const bf16x8 v11 = *(const bf16x8*)(Tl + ((size_t)(y1*W + x1))*256 + c0);
        bf16x8 o;
#pragma unroll
        for (int jj = 0; jj < 8; ++jj) {
            const float f00 = bf16_to_f32((unsigned short)v00[jj]);
            const float f01 = bf16_to_f32((unsigned short)v01[jj]);
            const float f10 = bf16_to_f32((unsigned short)v10[jj]);
            const float f11 = bf16_to_f32((unsigned short)v11[jj]);
            const float top = f00 + (f01 - f00) * wx;
            const float bot = f10 + (f11 - f10) * wx;
            o[jj] = (short)f32_to_bf16((top + (bot - top) * wy) * scale);
        }
        *(bf16x8*)(orow + pos * 256 + c0) = o;
    }
}

// ---------- fallback ROI (direct f32 gather) ----------
__global__ __launch_bounds__(256) void roi_direct_kernel(
    const float* __restrict__ feat2, const float* __restrict__ feat3,
    const float* __restrict__ feat4, const float* __restrict__ feat5,
    const float* __restrict__ rois, unsigned short* __restrict__ pooled)
{
    const int n = blockIdx.x;
    const int tid = threadIdx.x;
    __shared__ int sy0[7], sy1[7], sx0[7], sx1[7];
    __shared__ float swy[7], swx[7], svy[7], svx[7];
    const float rx1 = rois[n*4+0], ry1 = rois[n*4+1];
    const float rx2 = rois[n*4+2], ry2 = rois[n*4+3];
    int lvl = (int)rintf(log2f(sqrtf((ry2-ry1)*(rx2-rx1)) * (1.0f/224.0f))) + 4;
    lvl = lvl < 2 ? 2 : (lvl > 5 ? 5 : lvl);
    const int H = 256 >> (lvl - 2);
    const float Hm1 = (float)(H - 1);
    const float* feat = lvl==2 ? feat2 : (lvl==3 ? feat3 : (lvl==4 ? feat4 : feat5));
    if (tid < 7) {
        const float t = (float)tid / 6.0f;
        const float by1 = ry1*(1.0f/1024.0f), by2 = ry2*(1.0f/1024.0f);
        const float bx1 = rx1*(1.0f/1024.0f), bx2 = rx2*(1.0f/1024.0f);
        const float ys = (by1 + (by2-by1)*t) * Hm1;
        const float xs = (bx1 + (bx2-bx1)*t) * Hm1;
        const float yf = floorf(ys), xf = floorf(xs);
        swy[tid] = ys - yf;  swx[tid] = xs - xf;
        sy0[tid] = (int)fminf(fmaxf(yf,      0.0f), Hm1);
        sy1[tid] = (int)fminf(fmaxf(yf+1.0f, 0.0f), Hm1);
        sx0[tid] = (int)fminf(fmaxf(xf,      0.0f), Hm1);
        sx1[tid] = (int)fminf(fmaxf(xf+1.0f, 0.0f), Hm1);
        svy[tid] = (ys >= 0.0f && ys <= Hm1) ? 1.0f : 0.0f;
        svx[tid] = (xs >= 0.0f && xs <= Hm1) ? 1.0f : 0.0f;
    }
    __syncthreads();
    const int HW = H * H;
    unsigned short* orow = pooled + (size_t)n * POOLK;
    for (int e = tid; e < POOLK; e += 256) {
        const int c = e / 49, ij = e % 49, i = ij / 7, j = ij % 7;
        const float* p = feat + c * HW;
        const int y0 = sy0[i], y1 = sy1[i], x0 = sx0[j], x1 = sx1[j];
        const float wy = swy[i], wx = swx[j];
        const float v00 = p[y0*H + x0], v01 = p[y0*H + x1];
        const float v10 = p[y1*H + x0], v11 = p[y1*H + x1];
        float v = v00*(1.0f-wy)*(1.0f-wx) + v01*(1.0f-wy)*wx
                + v10*wy*(1.0f-wx)        + v11*wy*wx;
        v *= svy[i] * svx[j];
        orow[ij*256 + c] = f32_to_bf16(v);
    }
}

// ---------- f32 -> bf16 conversion ----------
__global__ void cvt_bf16_kernel(const float* __restrict__ src,
                                unsigned short* __restrict__ dst, int n)
{
    const int i = (blockIdx.x * 256 + threadIdx.x) * 4;
    if (i >= n) return;
    const float4 v = *(const float4*)(src + i);
    ushort4 o;
    o.x = f32_to_bf16(v.x); o.y = f32_to_bf16(v.y);
    o.z = f32_to_bf16(v.z); o.w = f32_to_bf16(v.w);
    *(ushort4*)(dst + i) = o;
}

// ---------- conv_w [o][c][ij] f32 -> bf16 [o][ij*256+c] ----------
__global__ __launch_bounds__(256) void convw_tr_kernel(
    const float* __restrict__ src, unsigned short* __restrict__ dst)
{
    const int o = blockIdx.x;
    const int t = threadIdx.x;
    __shared__ unsigned short wlds[POOLK];
    const float* srow = src + (size_t)o * POOLK;
    for (int it = 0; it < 49; ++it) {
        const int idx = it * 256 + t;
        wlds[idx] = f32_to_bf16(srow[idx]);
    }
    __syncthreads();
    unsigned short* drow = dst + (size_t)o * POOLK;
    for (int it = 0; it < 49; ++it) {
        const int k = it * 256 + t;
        const int c = k & 255, ij = k >> 8;
        drow[k] = wlds[c * 49 + ij];
    }
}

// ---------- bf16 BT-GEMM, 128x128 tile, BK=64 (+32 tail), split-K ----------
// 1-D grid of 64*nz blocks; z = bid % nz so (with nz==8) each XCD owns one
// K-slice entirely -> A/B panels fetched ~once per XCD (L2-resident window).
// LDS row = 128 B (full bank cycle) -> slot swizzle with (row&7): 2-way max.
__global__ __launch_bounds__(256, 2) void gemm_bt(
    const unsigned short* __restrict__ A, const unsigned short* __restrict__ B,
    float* __restrict__ Cpart, int K, int Kper, int nz)
{
    __shared__ __align__(16) unsigned short At[128*64];
    __shared__ __align__(16) unsigned short Bt[128*64];
    const int tid  = threadIdx.x;
    const int lane = tid & 63;
    const int bid  = blockIdx.x;
    const int z  = bid % nz;
    const int iq = bid / nz;
    const int bx = iq & 7, by = iq >> 3;
    const int wm = (tid >> 6) >> 1, wn = (tid >> 6) & 1;
    const size_t k0 = (size_t)z * Kper;

    // staging: thread -> LDS slot (r1 + 32p, q); linear dest tid*8 + p*2048
    const int r1 = tid >> 3;           // 0..31
    const int q  = tid & 7;
    const int csw = (q ^ (r1 & 7)) * 8;     // inverse-swizzled global column
    const unsigned short* Ag = A + ((size_t)(by * 128 + r1)) * K + k0 + csw;
    const unsigned short* Bg = B + ((size_t)(bx * 128 + r1)) * K + k0 + csw;

    f32x4 acc[4][4] = {};
    const int fr = lane & 15;
    const int fq = lane >> 4;
    const int sA = fr & 7;             // row-XOR for swizzled reads

    for (int k = 0; k < Kper; k += 64) {
#pragma unroll
        for (int p = 0; p < 4; ++p) {
            gld16(Ag + (size_t)(32 * p) * K + k, &At[p * 2048 + tid * 8]);
            gld16(Bg + (size_t)(32 * p) * K + k, &Bt[p * 2048 + tid * 8]);
        }
        asm volatile("s_waitcnt vmcnt(0)" ::: "memory");
        __syncthreads();

        bf16x8 a[4][2], b[4][2];
#pragma unroll
        for (int mi = 0; mi < 4; ++mi) {
            const int row = wm * 64 + mi * 16 + fr;
#pragma unroll
            for (int kk = 0; kk < 2; ++kk)
                a[mi][kk] = *(const bf16x8*)&At[row * 64 + ((kk * 4 + fq) ^ sA) * 8];
        }
#pragma unroll
        for (int ni = 0; ni < 4; ++ni) {
            const int row = wn * 64 + ni * 16 + fr;
#pragma unroll
            for (int kk = 0; kk < 2; ++kk)
                b[ni][kk] = *(const bf16x8*)&Bt[row * 64 + ((kk * 4 + fq) ^ sA) * 8];
        }
#pragma unroll
        for (int mi = 0; mi < 4; ++mi)
#pragma unroll
            for (int ni = 0; ni < 4; ++ni)
                acc[mi][ni] = __builtin_amdgcn_mfma_f32_16x16x32_bf16(
                    a[mi][0], b[ni][0], acc[mi][ni], 0, 0, 0);
        if (k + 32 < Kper) {
#pragma unroll
            for (int mi = 0; mi < 4; ++mi)
#pragma unroll
                for (int ni = 0; ni < 4; ++ni)
                    acc[mi][ni] = __builtin_amdgcn_mfma_f32_16x16x32_bf16(
                        a[mi][1], b[ni][1], acc[mi][ni], 0, 0, 0);
        }
        __syncthreads();
    }

    float* Cp = Cpart + (size_t)z * (1024 * 1024);
    const int row0 = by * 128 + wm * 64;
    const int col0 = bx * 128 + wn * 64;
#pragma unroll
    for (int mi = 0; mi < 4; ++mi)
#pragma unroll
        for (int ni = 0; ni < 4; ++ni)
#pragma unroll
            for (int r = 0; r < 4; ++r)
                Cp[(size_t)(row0 + mi*16 + fq*4 + r) * 1024 + col0 + ni*16 + fr]
                    = acc[mi][ni][r];
}

// ---------- reduce split-K partials + BN -> bf16 (float4) ----------
__global__ void reduce_bn_kernel(const float* __restrict__ part,
    const float* __restrict__ bias, const float* __restrict__ gamma,
    const float* __restrict__ beta, const float* __restrict__ mean,
    const float* __restrict__ var, unsigned short* __restrict__ out, int nz)
{
    const int i4 = (blockIdx.x * 256 + threadIdx.x) * 4;
    const int n = i4 & 1023;
    float4 v = make_float4(0.f, 0.f, 0.f, 0.f);
    for (int zz = 0; zz < nz; ++zz) {
        const float4 p = *(const float4*)(part + (size_t)zz * 1048576 + i4);
        v.x += p.x; v.y += p.y; v.z += p.z; v.w += p.w;
    }
    const float4 bi = *(const float4*)(bias + n);
    const float4 ga = *(const float4*)(gamma + n);
    const float4 be = *(const float4*)(beta + n);
    const float4 me = *(const float4*)(mean + n);
    const float4 va = *(const float4*)(var + n);
    ushort4 o;
    o.x = f32_to_bf16((v.x + bi.x - me.x) * __frsqrt_rn(va.x + 0.001f) * ga.x + be.x);
    o.y = f32_to_bf16((v.y + bi.y - me.y) * __frsqrt_rn(va.y + 0.001f) * ga.y + be.y);
    o.z = f32_to_bf16((v.z + bi.z - me.z) * __frsqrt_rn(va.z + 0.001f) * ga.z + be.z);
    o.w = f32_to_bf16((v.w + bi.w - me.w) * __frsqrt_rn(va.w + 0.001f) * ga.w + be.w);
    *(ushort4*)(out + i4) = o;
}

// ---------- fused 64x64 FC GEMM (K=1024, BK=64): bias + optional ReLU ----------
__global__ __launch_bounds__(256) void gemm64_fused(
    const unsigned short* __restrict__ A, const unsigned short* __restrict__ B,
    const float* __restrict__ bias, unsigned short* __restrict__ out, int relu)
{
    __shared__ __align__(16) unsigned short At[64*64];
    __shared__ __align__(16) unsigned short Bt[64*64];
    const int tid = threadIdx.x, lane = tid & 63;
    const int w = tid >> 6, wm = w >> 1, wn = w & 1;
    const int r1 = tid >> 3;           // 0..31
    const int q  = tid & 7;
    const int csw = (q ^ (r1 & 7)) * 8;
    const unsigned short* Ag = A + (size_t)(blockIdx.y*64 + r1) * 1024 + csw;
    const unsigned short* Bg = B + (size_t)(blockIdx.x*64 + r1) * 1024 + csw;
    const int fr = lane & 15, fq = lane >> 4;
    const int sA = fr & 7;
    f32x4 acc[2][2] = {};
    for (int k = 0; k < 1024; k += 64) {
#pragma unroll
        for (int p = 0; p < 2; ++p) {
            gld16(Ag + (size_t)(32 * p) * 1024 + k, &At[p * 2048 + tid * 8]);
            gld16(Bg + (size_t)(32 * p) * 1024 + k, &Bt[p * 2048 + tid * 8]);
        }
        asm volatile("s_waitcnt vmcnt(0)" ::: "memory");
        __syncthreads();
        bf16x8 a[2][2], b[2][2];
#pragma unroll
        for (int mi = 0; mi < 2; ++mi) {
            const int row = wm * 32 + mi * 16 + fr;
#pragma unroll
            for (int kk = 0; kk < 2; ++kk)
                a[mi][kk] = *(const bf16x8*)&At[row * 64 + ((kk * 4 + fq) ^ sA) * 8];
        }
#pragma unroll
        for (int ni = 0; ni < 2; ++ni) {
            const int row = wn * 32 + ni * 16 + fr;
#pragma unroll
            for (int kk = 0; kk < 2; ++kk)
                b[ni][kk] = *(const bf16x8*)&Bt[row * 64 + ((kk * 4 + fq) ^ sA) * 8];
        }
#pragma unroll
        for (int kk = 0; kk < 2; ++kk)
#pragma unroll
            for (int mi = 0; mi < 2; ++mi)
#pragma unroll
                for (int ni = 0; ni < 2; ++ni)
                    acc[mi][ni] = __builtin_amdgcn_mfma_f32_16x16x32_bf16(
                        a[mi][kk], b[ni][kk], acc[mi][ni], 0, 0, 0);
        __syncthreads();
    }
    const int row0 = blockIdx.y*64 + wm*32;
    const int col0 = blockIdx.x*64 + wn*32;
#pragma unroll
    for (int mi = 0; mi < 2; ++mi)
#pragma unroll
        for (int ni = 0; ni < 2; ++ni)
#pragma unroll
            for (int r = 0; r < 4; ++r) {
                const int row = row0 + mi*16 + fq*4 + r;
                const int col = col0 + ni*16 + fr;
                float v = acc[mi][ni][r] + bias[col];
                if (relu) v = fmaxf(v, 0.0f);
                out[(size_t)row * 1024 + col] = f32_to_bf16(v);
            }
}

// ---------- cls/bbox heads + softmax ----------
__global__ __launch_bounds__(256) void head_kernel(
    const unsigned short* __restrict__ h2,
    const float* __restrict__ cls_w, const float* __restrict__ cls_b,
    const float* __restrict__ bbox_w, const float* __restrict__ bbox_b,
    float* __restrict__ out)
{
    const int roi = blockIdx.x * 4 + (threadIdx.x >> 6);
    const int lane = threadIdx.x & 63;
    const unsigned short* hrow = h2 + (size_t)roi * 1024;
    float hv[16];
#pragma unroll
    for (int j = 0; j < 16; ++j)
        hv[j] = bf16_to_f32(hrow[lane*16 + j]);
    float r[10];
#pragma unroll
    for (int o = 0; o < 10; ++o) {
        const float* w = (o < 2) ? (cls_w + o*1024) : (bbox_w + (size_t)(o-2)*1024);
        float s = 0.f;
#pragma unroll
        for (int j = 0; j < 16; ++j) s += hv[j] * w[lane*16 + j];
#pragma unroll
        for (int off = 32; off > 0; off >>= 1) s += __shfl_xor(s, off);
        r[o] = s;
    }
    if (lane == 0) {
        const float l0 = r[0] + cls_b[0], l1 = r[1] + cls_b[1];
        out[roi*2+0] = l0; out[roi*2+1] = l1;
        const float m = fmaxf(l0, l1);
        const float e0 = expf(l0 - m), e1 = expf(l1 - m);
        const float inv = 1.0f / (e0 + e1);
        out[2000 + roi*2 + 0] = e0 * inv;
        out[2000 + roi*2 + 1] = e1 * inv;
#pragma unroll
        for (int qq = 0; qq < 8; ++qq) out[4000 + roi*8 + qq] = r[2+qq] + bbox_b[qq];
    }
}

// ---------- launcher ----------
extern "C" void kernel_launch(void* const* d_in, const int* in_sizes, int n_in,
                              void* d_out, int out_size, void* d_ws, size_t ws_size,
                              hipStream_t stream)
{
    const float* feat2   = (const float*)d_in[0];
    const float* feat3   = (const float*)d_in[1];
    const float* feat4   = (const float*)d_in[2];
    const float* feat5   = (const float*)d_in[3];
    const float* rois    = (const float*)d_in[4];
    const float* conv_w  = (const float*)d_in[5];
    const float* conv_b  = (const float*)d_in[6];
    const float* bn_gamma= (const float*)d_in[7];
    const float* bn_beta = (const float*)d_in[8];
    const float* bn_mean = (const float*)d_in[9];
    const float* bn_var  = (const float*)d_in[10];
    const float* fc1_w   = (const float*)d_in[11];
    const float* fc1_b   = (const float*)d_in[12];
    const float* fc2_w   = (const float*)d_in[13];
    const float* fc2_b   = (const float*)d_in[14];
    const float* cls_w   = (const float*)d_in[15];
    const float* cls_b   = (const float*)d_in[16];
    const float* bbox_w  = (const float*)d_in[17];
    const float* bbox_b  = (const float*)d_in[18];
    float* out = (float*)d_out;

    // tierA: T region (44.6 MB) aliased by 8 x 4 MB split-K partials
    const size_t fixedBytes = (size_t)25690112 + 25690112 + 5 * (size_t)2097152;
    const size_t needA = fixedBytes + (size_t)44564480;   // ~106.5 MB
    const size_t needB = fixedBytes + (size_t)16777216;   // ~79 MB fallback
    int tier = (ws_size >= needA) ? 1 : 2;
    (void)needB;
    const size_t regionA = tier == 1 ? (size_t)44564480 : (size_t)16777216;
    const int nzc  = tier == 1 ? 8 : 4;
    const int Kper = tier == 1 ? 1568 : 3136;

    char* ws = (char*)d_ws;
    size_t off = 0;
    auto alloc = [&](size_t bytes) {
        void* p = ws + off; off += (bytes + 255) & ~(size_t)255; return p;
    };
    char* rA = (char*)alloc(regionA);
    unsigned short* T    = (unsigned short*)rA;
    float*          part = (float*)rA;
    unsigned short* pooled   = (unsigned short*)alloc((size_t)1024 * POOLK * 2);
    unsigned short* convw_bf = (unsigned short*)alloc((size_t)1024 * POOLK * 2);
    unsigned short* fc1w_bf  = (unsigned short*)alloc((size_t)1048576 * 2);
    unsigned short* fc2w_bf  = (unsigned short*)alloc((size_t)1048576 * 2);
    unsigned short* ybf      = (unsigned short*)alloc((size_t)1048576 * 2);
    unsigned short* h1bf     = (unsigned short*)alloc((size_t)1048576 * 2);
    unsigned short* h2bf     = (unsigned short*)alloc((size_t)1048576 * 2);

    // weight conversions
    hipLaunchKernelGGL(cvt_bf16_kernel, dim3(1024), dim3(256), 0, stream,
                       fc1_w, fc1w_bf, 1048576);
    hipLaunchKernelGGL(cvt_bf16_kernel, dim3(1024), dim3(256), 0, stream,
                       fc2_w, fc2w_bf, 1048576);
    hipLaunchKernelGGL(convw_tr_kernel, dim3(1024), dim3(256), 0, stream,
                       conv_w, convw_bf);

    // zero pad rows 1000..1023 of pooled
    hipMemsetAsync(pooled + (size_t)1000 * POOLK, 0, (size_t)24 * POOLK * 2, stream);

    if (tier == 1) {
        hipLaunchKernelGGL(feat_tr_kernel, dim3(2720), dim3(256), 0, stream,
                           feat2, feat3, feat4, feat5, T);
        hipLaunchKernelGGL(roi_gather_kernel, dim3(1000), dim3(256), 0, stream,
                           T, rois, pooled);
    } else {
        hipLaunchKernelGGL(roi_direct_kernel, dim3(1000), dim3(256), 0, stream,
                           feat2, feat3, feat4, feat5, rois, pooled);
    }

    // conv einsum GEMM, split-K (XCD-aligned when nz==8)
    hipLaunchKernelGGL(gemm_bt, dim3(64 * nzc), dim3(256), 0, stream,
                       pooled, convw_bf, part, POOLK, Kper, nzc);
    hipLaunchKernelGGL(reduce_bn_kernel, dim3(1024), dim3(256), 0, stream,
                       part, conv_b, bn_gamma, bn_beta, bn_mean, bn_var, ybf, nzc);

    // fc1 + relu, fc2 + relu
    hipLaunchKernelGGL(gemm64_fused, dim3(16, 16), dim3(256), 0, stream,
                       ybf, fc1w_bf, fc1_b, h1bf, 1);
    hipLaunchKernelGGL(gemm64_fused, dim3(16, 16), dim3(256), 0, stream,
                       h1bf, fc2w_bf, fc2_b, h2bf, 1);

    // heads + softmax
    hipLaunchKernelGGL(head_kernel, dim3(250), dim3(256), 0, stream,
                       h2bf, cls_w, cls_b, bbox_w, bbox_b, out);
}

// Round 4
// 128.124 us; speedup vs baseline: 1.6894x; 1.0358x over previous
//
#include <hip/hip_runtime.h>
#include <cstdint>
#include <cstddef>

typedef __attribute__((ext_vector_type(8))) short bf16x8;
typedef __attribute__((ext_vector_type(4))) float f32x4;

#define POOLK 12544   // K order: ij*256 + c

// T (channel-last bf16 feats) level offsets in shorts
#define TOFF2 0
#define TOFF3 16777216
#define TOFF4 20971520
#define TOFF5 22020096

__device__ __forceinline__ void gld16(const void* g, void* l) {
    __builtin_amdgcn_global_load_lds(
        (const __attribute__((address_space(1))) void*)g,
        (__attribute__((address_space(3))) void*)l, 16, 0, 0);
}
__device__ __forceinline__ unsigned short f32_to_bf16(float f) {
    union { float f; unsigned u; } x; x.f = f;
    return (unsigned short)((x.u + 0x7FFFu + ((x.u >> 16) & 1u)) >> 16);
}
__device__ __forceinline__ float bf16_to_f32(unsigned short s) {
    return __uint_as_float(((unsigned)s) << 16);
}

// ---------- merged prep: feat transpose + convw transpose + fc weight cvt ----------
// blocks [0,2720): feat_tr ; [2720,4768): convw halves ; [4768,5792): fc1 ; [5792,6816): fc2
__global__ __launch_bounds__(256) void prep_kernel(
    const float* __restrict__ f2, const float* __restrict__ f3,
    const float* __restrict__ f4, const float* __restrict__ f5,
    unsigned short* __restrict__ T,
    const float* __restrict__ conv_w, unsigned short* __restrict__ convw_bf,
    const float* __restrict__ fc1_w, unsigned short* __restrict__ fc1w_bf,
    const float* __restrict__ fc2_w, unsigned short* __restrict__ fc2w_bf,
    int do_feat)
{
    __shared__ __align__(16) unsigned short sh[8192];   // 16 KB
    const int t = threadIdx.x;
    int b = blockIdx.x;

    if (b < 2720) {                      // ---- feature transpose, 32 pos x 256 ch
        if (!do_feat) return;
        const float* src; unsigned short* dst; int P;
        if (b < 2048)      { src = f2; dst = T + TOFF2; P = 65536; }
        else if (b < 2560) { src = f3; dst = T + TOFF3; P = 16384; b -= 2048; }
        else if (b < 2688) { src = f4; dst = T + TOFF4; P = 4096;  b -= 2560; }
        else               { src = f5; dst = T + TOFF5; P = 1024;  b -= 2688; }
        const int p0 = b * 32;
        const int cr = t >> 3, x4 = (t & 7) * 4;
#pragma unroll
        for (int cc = 0; cc < 8; ++cc) {
            const int c = cc * 32 + cr;
            const float4 v = *(const float4*)(src + (size_t)c * P + p0 + x4);
            const int blk = c >> 3, cl = c & 7;
            float vv[4] = {v.x, v.y, v.z, v.w};
#pragma unroll
            for (int i = 0; i < 4; ++i) {
                const int p = x4 + i;
                sh[p * 256 + ((blk ^ (p >> 2)) << 3) + cl] = f32_to_bf16(vv[i]);
            }
        }
        __syncthreads();
        const int cb = t & 31;           // channel-block 0..31 (8 ch each)
#pragma unroll
        for (int pz = 0; pz < 4; ++pz) {
            const int pp = pz * 8 + (t >> 5);
            const bf16x8 v = *(const bf16x8*)&sh[pp * 256 + ((cb ^ (pp >> 2)) << 3)];
            *(bf16x8*)(dst + (size_t)(p0 + pp) * 256 + cb * 8) = v;
        }
        return;
    }
    b -= 2720;
    if (b < 2048) {                      // ---- conv_w [o][c][ij] -> [o][ij*256+c], half-channel per block
        const int o = b >> 1, half = b & 1;
        const float* srow = conv_w + (size_t)o * POOLK + half * 6272;
        for (int k = t; k < 6272; k += 256) sh[k] = f32_to_bf16(srow[k]);
        __syncthreads();
        unsigned short* drow = convw_bf + (size_t)o * POOLK + half * 128;
        for (int k = t; k < 6272; k += 256) {
            const int ij = k >> 7, cl = k & 127;
            drow[ij * 256 + cl] = sh[cl * 49 + ij];
        }
        return;
    }
    b -= 2048;
    {                                     // ---- fc weight conversions
        const float* src = (b < 1024) ? fc1_w : fc2_w;
        unsigned short* dst = (b < 1024) ? fc1w_bf : fc2w_bf;
        const int bb = b & 1023;
        const int i = (bb * 256 + t) * 4;
        const float4 v = *(const float4*)(src + i);
        ushort4 o;
        o.x = f32_to_bf16(v.x); o.y = f32_to_bf16(v.y);
        o.z = f32_to_bf16(v.z); o.w = f32_to_bf16(v.w);
        *(ushort4*)(dst + i) = o;
    }
}

// ---------- ROI gather from channel-last T; pooled[n][ij*256+c]; zeroes pad rows ----------
__global__ __launch_bounds__(256) void roi_gather_kernel(
    const unsigned short* __restrict__ T, const float* __restrict__ rois,
    unsigned short* __restrict__ pooled, int nroi)
{
    const int n = blockIdx.x;
    const int tid = threadIdx.x;
    unsigned short* orow = pooled + (size_t)n * POOLK;
    if (n >= nroi) {                      // zero pad rows (keeps GEMM M=1024 exact)
        const bf16x8 z = {};
        for (int k = tid * 8; k < POOLK; k += 2048) *(bf16x8*)(orow + k) = z;
        return;
    }
    __shared__ int sy0[7], sy1[7], sx0[7], sx1[7];
    __shared__ float swy[7], swx[7], svy[7], svx[7];

    const float rx1 = rois[n*4+0], ry1 = rois[n*4+1];
    const float rx2 = rois[n*4+2], ry2 = rois[n*4+3];
    int lvl = (int)rintf(log2f(sqrtf((ry2-ry1)*(rx2-rx1)) * (1.0f/224.0f))) + 4;
    lvl = lvl < 2 ? 2 : (lvl > 5 ? 5 : lvl);
    const int W = 256 >> (lvl - 2);
    const float Hm1 = (float)(W - 1);
    const unsigned short* Tl = T + (lvl == 2 ? TOFF2 : (lvl == 3 ? TOFF3 : (lvl == 4 ? TOFF4 : TOFF5)));

    if (tid < 7) {
        const float t = (float)tid / 6.0f;
        const float by1 = ry1*(1.0f/1024.0f), by2 = ry2*(1.0f/1024.0f);
        const float bx1 = rx1*(1.0f/1024.0f), bx2 = rx2*(1.0f/1024.0f);
        const float ys = (by1 + (by2 - by1) * t) * Hm1;
        const float xs = (bx1 + (bx2 - bx1) * t) * Hm1;
        const float yf = floorf(ys), xf = floorf(xs);
        swy[tid] = ys - yf;  swx[tid] = xs - xf;
        sy0[tid] = (int)fminf(fmaxf(yf,        0.0f), Hm1);
        sy1[tid] = (int)fminf(fmaxf(yf + 1.0f, 0.0f), Hm1);
        sx0[tid] = (int)fminf(fmaxf(xf,        0.0f), Hm1);
        sx1[tid] = (int)fminf(fmaxf(xf + 1.0f, 0.0f), Hm1);
        svy[tid] = (ys >= 0.0f && ys <= Hm1) ? 1.0f : 0.0f;
        svx[tid] = (xs >= 0.0f && xs <= Hm1) ? 1.0f : 0.0f;
    }
    __syncthreads();

    const int g  = tid >> 5;
    const int c0 = (tid & 31) * 8;
#pragma unroll
    for (int it = 0; it < 7; ++it) {
        const int pos = it * 8 + g;
        if (pos >= 49) break;
        const int i = pos / 7, j = pos % 7;
        const int y0 = sy0[i], y1 = sy1[i], x0 = sx0[j], x1 = sx1[j];
        const float wy = swy[i], wx = swx[j];
        const float scale = svy[i] * svx[j];
        const bf16x8 v00 = *(const bf16x8*)(Tl + ((size_t)(y0*W + x0))*256 + c0);
        const bf16x8 v01 = *(const bf16x8*)(Tl + ((size_t)(y0*W + x1))*256 + c0);
        const bf16x8 v10 = *(const bf16x8*)(Tl + ((size_t)(y1*W + x0))*256 + c0);
        const bf16x8 v11 = *(const bf16x8*)(Tl + ((size_t)(y1*W + x1))*256 + c0);
        bf16x8 o;
#pragma unroll
        for (int jj = 0; jj < 8; ++jj) {
            const float f00 = bf16_to_f32((unsigned short)v00[jj]);
            const float f01 = bf16_to_f32((unsigned short)v01[jj]);
            const float f10 = bf16_to_f32((unsigned short)v10[jj]);
            const float f11 = bf16_to_f32((unsigned short)v11[jj]);
            const float top = f00 + (f01 - f00) * wx;
            const float bot = f10 + (f11 - f10) * wx;
            o[jj] = (short)f32_to_bf16((top + (bot - top) * wy) * scale);
        }
        *(bf16x8*)(orow + pos * 256 + c0) = o;
    }
}

// ---------- fallback ROI (direct f32 gather), also zeroes pad rows ----------
__global__ __launch_bounds__(256) void roi_direct_kernel(
    const float* __restrict__ feat2, const float* __restrict__ feat3,
    const float* __restrict__ feat4, const float* __restrict__ feat5,
    const float* __restrict__ rois, unsigned short* __restrict__ pooled, int nroi)
{
    const int n = blockIdx.x;
    const int tid = threadIdx.x;
    unsigned short* orow = pooled + (size_t)n * POOLK;
    if (n >= nroi) {
        const bf16x8 z = {};
        for (int k = tid * 8; k < POOLK; k += 2048) *(bf16x8*)(orow + k) = z;
        return;
    }
    __shared__ int sy0[7], sy1[7], sx0[7], sx1[7];
    __shared__ float swy[7], swx[7], svy[7], svx[7];
    const float rx1 = rois[n*4+0], ry1 = rois[n*4+1];
    const float rx2 = rois[n*4+2], ry2 = rois[n*4+3];
    int lvl = (int)rintf(log2f(sqrtf((ry2-ry1)*(rx2-rx1)) * (1.0f/224.0f))) + 4;
    lvl = lvl < 2 ? 2 : (lvl > 5 ? 5 : lvl);
    const int H = 256 >> (lvl - 2);
    const float Hm1 = (float)(H - 1);
    const float* feat = lvl==2 ? feat2 : (lvl==3 ? feat3 : (lvl==4 ? feat4 : feat5));
    if (tid < 7) {
        const float t = (float)tid / 6.0f;
        const float by1 = ry1*(1.0f/1024.0f), by2 = ry2*(1.0f/1024.0f);
        const float bx1 = rx1*(1.0f/1024.0f), bx2 = rx2*(1.0f/1024.0f);
        const float ys = (by1 + (by2-by1)*t) * Hm1;
        const float xs = (bx1 + (bx2-bx1)*t) * Hm1;
        const float yf = floorf(ys), xf = floorf(xs);
        swy[tid] = ys - yf;  swx[tid] = xs - xf;
        sy0[tid] = (int)fminf(fmaxf(yf,      0.0f), Hm1);
        sy1[tid] = (int)fminf(fmaxf(yf+1.0f, 0.0f), Hm1);
        sx0[tid] = (int)fminf(fmaxf(xf,      0.0f), Hm1);
        sx1[tid] = (int)fminf(fmaxf(xf+1.0f, 0.0f), Hm1);
        svy[tid] = (ys >= 0.0f && ys <= Hm1) ? 1.0f : 0.0f;
        svx[tid] = (xs >= 0.0f && xs <= Hm1) ? 1.0f : 0.0f;
    }
    __syncthreads();
    const int HW = H * H;
    for (int e = tid; e < POOLK; e += 256) {
        const int c = e / 49, ij = e % 49, i = ij / 7, j = ij % 7;
        const float* p = feat + c * HW;
        const int y0 = sy0[i], y1 = sy1[i], x0 = sx0[j], x1 = sx1[j];
        const float wy = swy[i], wx = swx[j];
        const float v00 = p[y0*H + x0], v01 = p[y0*H + x1];
        const float v10 = p[y1*H + x0], v11 = p[y1*H + x1];
        float v = v00*(1.0f-wy)*(1.0f-wx) + v01*(1.0f-wy)*wx
                + v10*wy*(1.0f-wx)        + v11*wy*wx;
        v *= svy[i] * svx[j];
        orow[ij*256 + c] = f32_to_bf16(v);
    }
}

// ---------- bf16 BT-GEMM, 128x128 tile, BK=32, DOUBLE-BUFFERED, split-K ----------
// grid 64*nz 1-D; z = bid % nz -> XCD-aligned K-slices (nz==8).
// Pipeline: issue next-tile gld16 into buf^1, vmcnt(4) (cur done, next in flight),
// barrier, ds_read+MFMA, barrier, swap. Loads land under the MFMA phase.
__global__ __launch_bounds__(256, 2) void gemm_bt(
    const unsigned short* __restrict__ A, const unsigned short* __restrict__ B,
    float* __restrict__ Cpart, int K, int Kper, int nz)
{
    __shared__ __align__(16) unsigned short At[2][128*32];
    __shared__ __align__(16) unsigned short Bt[2][128*32];
    const int tid  = threadIdx.x;
    const int lane = tid & 63;
    const int bid  = blockIdx.x;
    const int z  = bid % nz;
    const int iq = bid / nz;
    const int bx = iq & 7, by = iq >> 3;
    const int wm = (tid >> 6) >> 1, wn = (tid >> 6) & 1;
    const size_t k0 = (size_t)z * Kper;

    const int r1 = tid >> 2;          // 0..63
    const int q  = tid & 3;
    const int csw = (q ^ (r1 & 3)) * 8;     // inverse-swizzled source column
    const unsigned short* Ag = A + ((size_t)(by * 128 + r1)) * K + k0 + csw;
    const unsigned short* Bg = B + ((size_t)(bx * 128 + r1)) * K + k0 + csw;
    const int nit = Kper >> 5;

    gld16(Ag,                  &At[0][tid * 8]);
    gld16(Ag + (size_t)64 * K, &At[0][(tid + 256) * 8]);
    gld16(Bg,                  &Bt[0][tid * 8]);
    gld16(Bg + (size_t)64 * K, &Bt[0][(tid + 256) * 8]);

    f32x4 acc[4][4] = {};
    const int fr = lane & 15;
    const int fq = lane >> 4;
    const int rslot = (fq ^ (fr & 3)) * 8;

    int buf = 0;
    for (int it = 0; it < nit; ++it) {
        if (it + 1 < nit) {
            const size_t ko = (size_t)(it + 1) * 32;
            gld16(Ag + ko,                  &At[buf ^ 1][tid * 8]);
            gld16(Ag + (size_t)64 * K + ko, &At[buf ^ 1][(tid + 256) * 8]);
            gld16(Bg + ko,                  &Bt[buf ^ 1][tid * 8]);
            gld16(Bg + (size_t)64 * K + ko, &Bt[buf ^ 1][(tid + 256) * 8]);
            asm volatile("s_waitcnt vmcnt(4)" ::: "memory");
        } else {
            asm volatile("s_waitcnt vmcnt(0)" ::: "memory");
        }
        __syncthreads();

        bf16x8 a[4], b[4];
#pragma unroll
        for (int mi = 0; mi < 4; ++mi)
            a[mi] = *(const bf16x8*)&At[buf][(wm*64 + mi*16 + fr) * 32 + rslot];
#pragma unroll
        for (int ni = 0; ni < 4; ++ni)
            b[ni] = *(const bf16x8*)&Bt[buf][(wn*64 + ni*16 + fr) * 32 + rslot];
        __builtin_amdgcn_s_setprio(1);
#pragma unroll
        for (int mi = 0; mi < 4; ++mi)
#pragma unroll
            for (int ni = 0; ni < 4; ++ni)
                acc[mi][ni] = __builtin_amdgcn_mfma_f32_16x16x32_bf16(
                    a[mi], b[ni], acc[mi][ni], 0, 0, 0);
        __builtin_amdgcn_s_setprio(0);
        __syncthreads();
        buf ^= 1;
    }

    float* Cp = Cpart + (size_t)z * (1024 * 1024);
    const int row0 = by * 128 + wm * 64;
    const int col0 = bx * 128 + wn * 64;
#pragma unroll
    for (int mi = 0; mi < 4; ++mi)
#pragma unroll
        for (int ni = 0; ni < 4; ++ni)
#pragma unroll
            for (int r = 0; r < 4; ++r)
                Cp[(size_t)(row0 + mi*16 + fq*4 + r) * 1024 + col0 + ni*16 + fr]
                    = acc[mi][ni][r];
}

// ---------- reduce split-K partials + BN -> bf16 ----------
__global__ void reduce_bn_kernel(const float* __restrict__ part,
    const float* __restrict__ bias, const float* __restrict__ gamma,
    const float* __restrict__ beta, const float* __restrict__ mean,
    const float* __restrict__ var, unsigned short* __restrict__ out, int nz)
{
    const int i4 = (blockIdx.x * 256 + threadIdx.x) * 4;
    const int n = i4 & 1023;
    float4 v = make_float4(0.f, 0.f, 0.f, 0.f);
    for (int zz = 0; zz < nz; ++zz) {
        const float4 p = *(const float4*)(part + (size_t)zz * 1048576 + i4);
        v.x += p.x; v.y += p.y; v.z += p.z; v.w += p.w;
    }
    const float4 bi = *(const float4*)(bias + n);
    const float4 ga = *(const float4*)(gamma + n);
    const float4 be = *(const float4*)(beta + n);
    const float4 me = *(const float4*)(mean + n);
    const float4 va = *(const float4*)(var + n);
    ushort4 o;
    o.x = f32_to_bf16((v.x + bi.x - me.x) * __frsqrt_rn(va.x + 0.001f) * ga.x + be.x);
    o.y = f32_to_bf16((v.y + bi.y - me.y) * __frsqrt_rn(va.y + 0.001f) * ga.y + be.y);
    o.z = f32_to_bf16((v.z + bi.z - me.z) * __frsqrt_rn(va.z + 0.001f) * ga.z + be.z);
    o.w = f32_to_bf16((v.w + bi.w - me.w) * __frsqrt_rn(va.w + 0.001f) * ga.w + be.w);
    *(ushort4*)(out + i4) = o;
}

// ---------- fused 64x64 FC GEMM (K=1024, BK=32, double-buffered) ----------
__global__ __launch_bounds__(256) void gemm64_fused(
    const unsigned short* __restrict__ A, const unsigned short* __restrict__ B,
    const float* __restrict__ bias, unsigned short* __restrict__ out, int relu)
{
    __shared__ __align__(16) unsigned short At[2][64*32];
    __shared__ __align__(16) unsigned short Bt[2][64*32];
    const int tid = threadIdx.x, lane = tid & 63;
    const int w = tid >> 6, wm = w >> 1, wn = w & 1;
    const int r1 = tid >> 2;           // 0..63
    const int q  = tid & 3;
    const int csw = (q ^ (r1 & 3)) * 8;
    const unsigned short* Ag = A + (size_t)(blockIdx.y*64 + r1) * 1024 + csw;
    const unsigned short* Bg = B + (size_t)(blockIdx.x*64 + r1) * 1024 + csw;
    const int fr = lane & 15, fq = lane >> 4;
    const int rslot = (fq ^ (fr & 3)) * 8;

    gld16(Ag, &At[0][tid * 8]);
    gld16(Bg, &Bt[0][tid * 8]);

    f32x4 acc[2][2] = {};
    int buf = 0;
    for (int it = 0; it < 32; ++it) {
        if (it + 1 < 32) {
            const int ko = (it + 1) * 32;
            gld16(Ag + ko, &At[buf ^ 1][tid * 8]);
            gld16(Bg + ko, &Bt[buf ^ 1][tid * 8]);
            asm volatile("s_waitcnt vmcnt(2)" ::: "memory");
        } else {
            asm volatile("s_waitcnt vmcnt(0)" ::: "memory");
        }
        __syncthreads();
        bf16x8 a[2], b[2];
#pragma unroll
        for (int mi = 0; mi < 2; ++mi)
            a[mi] = *(const bf16x8*)&At[buf][(wm*32 + mi*16 + fr) * 32 + rslot];
#pragma unroll
        for (int ni = 0; ni < 2; ++ni)
            b[ni] = *(const bf16x8*)&Bt[buf][(wn*32 + ni*16 + fr) * 32 + rslot];
        __builtin_amdgcn_s_setprio(1);
#pragma unroll
        for (int mi = 0; mi < 2; ++mi)
#pragma unroll
            for (int ni = 0; ni < 2; ++ni)
                acc[mi][ni] = __builtin_amdgcn_mfma_f32_16x16x32_bf16(
                    a[mi], b[ni], acc[mi][ni], 0, 0, 0);
        __builtin_amdgcn_s_setprio(0);
        __syncthreads();
        buf ^= 1;
    }
    const int row0 = blockIdx.y*64 + wm*32;
    const int col0 = blockIdx.x*64 + wn*32;
#pragma unroll
    for (int mi = 0; mi < 2; ++mi)
#pragma unroll
        for (int ni = 0; ni < 2; ++ni)
#pragma unroll
            for (int r = 0; r < 4; ++r) {
                const int row = row0 + mi*16 + fq*4 + r;
                const int col = col0 + ni*16 + fr;
                float v = acc[mi][ni][r] + bias[col];
                if (relu) v = fmaxf(v, 0.0f);
                out[(size_t)row * 1024 + col] = f32_to_bf16(v);
            }
}

// ---------- cls/bbox heads + softmax ----------
__global__ __launch_bounds__(256) void head_kernel(
    const unsigned short* __restrict__ h2,
    const float* __restrict__ cls_w, const float* __restrict__ cls_b,
    const float* __restrict__ bbox_w, const float* __restrict__ bbox_b,
    float* __restrict__ out)
{
    const int roi = blockIdx.x * 4 + (threadIdx.x >> 6);
    const int lane = threadIdx.x & 63;
    const unsigned short* hrow = h2 + (size_t)roi * 1024;
    float hv[16];
#pragma unroll
    for (int j = 0; j < 16; ++j)
        hv[j] = bf16_to_f32(hrow[lane*16 + j]);
    float r[10];
#pragma unroll
    for (int o = 0; o < 10; ++o) {
        const float* w = (o < 2) ? (cls_w + o*1024) : (bbox_w + (size_t)(o-2)*1024);
        float s = 0.f;
#pragma unroll
        for (int j = 0; j < 16; ++j) s += hv[j] * w[lane*16 + j];
#pragma unroll
        for (int off = 32; off > 0; off >>= 1) s += __shfl_xor(s, off);
        r[o] = s;
    }
    if (lane == 0) {
        const float l0 = r[0] + cls_b[0], l1 = r[1] + cls_b[1];
        out[roi*2+0] = l0; out[roi*2+1] = l1;
        const float m = fmaxf(l0, l1);
        const float e0 = expf(l0 - m), e1 = expf(l1 - m);
        const float inv = 1.0f / (e0 + e1);
        out[2000 + roi*2 + 0] = e0 * inv;
        out[2000 + roi*2 + 1] = e1 * inv;
#pragma unroll
        for (int qq = 0; qq < 8; ++qq) out[4000 + roi*8 + qq] = r[2+qq] + bbox_b[qq];
    }
}

// ---------- launcher ----------
extern "C" void kernel_launch(void* const* d_in, const int* in_sizes, int n_in,
                              void* d_out, int out_size, void* d_ws, size_t ws_size,
                              hipStream_t stream)
{
    const float* feat2   = (const float*)d_in[0];
    const float* feat3   = (const float*)d_in[1];
    const float* feat4   = (const float*)d_in[2];
    const float* feat5   = (const float*)d_in[3];
    const float* rois    = (const float*)d_in[4];
    const float* conv_w  = (const float*)d_in[5];
    const float* conv_b  = (const float*)d_in[6];
    const float* bn_gamma= (const float*)d_in[7];
    const float* bn_beta = (const float*)d_in[8];
    const float* bn_mean = (const float*)d_in[9];
    const float* bn_var  = (const float*)d_in[10];
    const float* fc1_w   = (const float*)d_in[11];
    const float* fc1_b   = (const float*)d_in[12];
    const float* fc2_w   = (const float*)d_in[13];
    const float* fc2_b   = (const float*)d_in[14];
    const float* cls_w   = (const float*)d_in[15];
    const float* cls_b   = (const float*)d_in[16];
    const float* bbox_w  = (const float*)d_in[17];
    const float* bbox_b  = (const float*)d_in[18];
    float* out = (float*)d_out;
    const int nroi = in_sizes[4] / 4;

    const size_t fixedBytes = (size_t)25690112 + 25690112 + 5 * (size_t)2097152;
    const size_t needA = fixedBytes + (size_t)44564480;   // ~106.5 MB
    const int tier = (ws_size >= needA) ? 1 : 2;
    const size_t regionA = tier == 1 ? (size_t)44564480 : (size_t)16777216;
    const int nzc  = tier == 1 ? 8 : 4;
    const int Kper = tier == 1 ? 1568 : 3136;

    char* ws = (char*)d_ws;
    size_t off = 0;
    auto alloc = [&](size_t bytes) {
        void* p = ws + off; off += (bytes + 255) & ~(size_t)255; return p;
    };
    char* rA = (char*)alloc(regionA);     // T feats (early) aliased by split-K partials (late)
    unsigned short* T    = (unsigned short*)rA;
    float*          part = (float*)rA;
    unsigned short* pooled   = (unsigned short*)alloc((size_t)1024 * POOLK * 2);
    unsigned short* convw_bf = (unsigned short*)alloc((size_t)1024 * POOLK * 2);
    unsigned short* fc1w_bf  = (unsigned short*)alloc((size_t)1048576 * 2);
    unsigned short* fc2w_bf  = (unsigned short*)alloc((size_t)1048576 * 2);
    unsigned short* ybf      = (unsigned short*)alloc((size_t)1048576 * 2);
    unsigned short* h1bf     = (unsigned short*)alloc((size_t)1048576 * 2);
    unsigned short* h2bf     = (unsigned short*)alloc((size_t)1048576 * 2);

    // merged prep: feat transpose + convw transpose + fc cvts
    hipLaunchKernelGGL(prep_kernel, dim3(6816), dim3(256), 0, stream,
                       feat2, feat3, feat4, feat5, T,
                       conv_w, convw_bf, fc1_w, fc1w_bf, fc2_w, fc2w_bf,
                       tier == 1 ? 1 : 0);

    if (tier == 1) {
        hipLaunchKernelGGL(roi_gather_kernel, dim3(1024), dim3(256), 0, stream,
                           T, rois, pooled, nroi);
    } else {
        hipLaunchKernelGGL(roi_direct_kernel, dim3(1024), dim3(256), 0, stream,
                           feat2, feat3, feat4, feat5, rois, pooled, nroi);
    }

    // conv einsum GEMM, double-buffered split-K (XCD-aligned when nz==8)
    hipLaunchKernelGGL(gemm_bt, dim3(64 * nzc), dim3(256), 0, stream,
                       pooled, convw_bf, part, POOLK, Kper, nzc);
    hipLaunchKernelGGL(reduce_bn_kernel, dim3(1024), dim3(256), 0, stream,
                       part, conv_b, bn_gamma, bn_beta, bn_mean, bn_var, ybf, nzc);

    // fc1 + relu, fc2 + relu
    hipLaunchKernelGGL(gemm64_fused, dim3(16, 16), dim3(256), 0, stream,
                       ybf, fc1w_bf, fc1_b, h1bf, 1);
    hipLaunchKernelGGL(gemm64_fused, dim3(16, 16), dim3(256), 0, stream,
                       h1bf, fc2w_bf, fc2_b, h2bf, 1);

    // heads + softmax
    hipLaunchKernelGGL(head_kernel, dim3(250), dim3(256), 0, stream,
                       h2bf, cls_w, cls_b, bbox_w, bbox_b, out);
}